// Round 10
// baseline (680.753 us; speedup 1.0000x reference)
//
#include <hip/hip_runtime.h>

#define N_NODES 50000
#define D_NB 16
#define IN_DIM 256
#define OUT_DIM 128
#define K_HEADS 4
#define SLOPE 0.01f
#define NSLICE 16       // slice s = k*4 + cb; 32 cols each
#define SLICE_COLS 32
#define CH 16           // nodes per work-steal chunk

typedef __attribute__((ext_vector_type(8))) short short8;
typedef __attribute__((ext_vector_type(4))) float f32x4;
typedef __attribute__((ext_vector_type(2))) float f32x2;

static __device__ __forceinline__ unsigned short f2bf(float f) {
    unsigned u = __float_as_uint(f);
    unsigned r = u + 0x7fffu + ((u >> 16) & 1u);   // RNE
    return (unsigned short)(r >> 16);
}
static __device__ __forceinline__ float bf2f(unsigned short b) {
    return __uint_as_float(((unsigned)b) << 16);
}

// ---------------- Kernel 0: W (f32) -> Wb (bf16), same [K][OUT][IN] layout ----------------
__global__ void wb_kernel(const float* __restrict__ W, unsigned short* __restrict__ Wb) {
    int id = blockIdx.x * blockDim.x + threadIdx.x;
    if (id < K_HEADS * OUT_DIM * IN_DIM) Wb[id] = f2bf(W[id]);
}

// ---------------- Kernel 1: MFMA GEMM, 64 rows/block, 16 x 16KB double-buffered stages ----------
// e output layout now [k][N] (per-head contiguous) for slice-local attn gathers.
__global__ __launch_bounds__(256) void gemm_kernel(
    const float* __restrict__ X, const unsigned short* __restrict__ Wb,
    const float* __restrict__ a,
    unsigned short* __restrict__ Whb2, float* __restrict__ e_nb, float* __restrict__ e_self)
{
    __shared__ unsigned short Wlds[2][SLICE_COLS * IN_DIM];   // 2 x 16 KB

    const int t = threadIdx.x;
    const int lane = t & 63;
    const int w = t >> 6;
    const int lrow = lane & 15;
    const int lk = lane >> 4;
    const int m0 = blockIdx.x * 64 + w * 16;

    const int arow = m0 + lrow;
    const bool avalid = arow < N_NODES;

    const float* Xr = X + (size_t)arow * IN_DIM + lk * 8;
    short8 af[8];
    #pragma unroll
    for (int kk = 0; kk < 8; ++kk) {
        short8 s;
        if (avalid) {
            float4 x0 = *(const float4*)(Xr + kk * 32);
            float4 x1 = *(const float4*)(Xr + kk * 32 + 4);
            s[0] = (short)f2bf(x0.x); s[1] = (short)f2bf(x0.y);
            s[2] = (short)f2bf(x0.z); s[3] = (short)f2bf(x0.w);
            s[4] = (short)f2bf(x1.x); s[5] = (short)f2bf(x1.y);
            s[6] = (short)f2bf(x1.z); s[7] = (short)f2bf(x1.w);
        } else {
            s = short8{0, 0, 0, 0, 0, 0, 0, 0};
        }
        af[kk] = s;
    }

    auto STAGE = [&](int st, int buf) {
        const unsigned short* WbS = Wb + (size_t)st * SLICE_COLS * IN_DIM;
        #pragma unroll
        for (int i = 0; i < 4; ++i) {
            const int c = i * 256 + t;
            const int r = c >> 5;
            const int p = c & 31;
            const int cu = p ^ (r & 7);
            const unsigned short* gsrc = WbS + r * IN_DIM + cu * 8;
            unsigned short* ldst = &Wlds[buf][c * 8];
            __builtin_amdgcn_global_load_lds(
                (const __attribute__((address_space(1))) void*)gsrc,
                (__attribute__((address_space(3))) void*)ldst, 16, 0, 0);
        }
    };

    float pnb = 0.f, psf = 0.f;
    STAGE(0, 0);
    __syncthreads();

    for (int st = 0; st < NSLICE; ++st) {
        const int buf = st & 1;
        if (st + 1 < NSLICE) STAGE(st + 1, buf ^ 1);

        f32x4 acc[2] = {};
        #pragma unroll
        for (int kk = 0; kk < 8; ++kk) {
            #pragma unroll
            for (int nt = 0; nt < 2; ++nt) {
                const int row = nt * 16 + lrow;
                const int pos = (kk * 4 + lk) ^ (row & 7);
                const short8 bf = *(const short8*)(&Wlds[buf][row * IN_DIM + pos * 8]);
                acc[nt] = __builtin_amdgcn_mfma_f32_16x16x32_bf16(bf, af[kk], acc[nt], 0, 0, 0);
            }
        }

        const int k = st >> 2, cb = st & 3;
        #pragma unroll
        for (int nt = 0; nt < 2; ++nt) {
            const float4 anb = *(const float4*)(a + k * 2 * OUT_DIM + cb * 32 + nt * 16 + lk * 4);
            const float4 asf = *(const float4*)(a + k * 2 * OUT_DIM + OUT_DIM + cb * 32 + nt * 16 + lk * 4);
            pnb += acc[nt][0] * anb.x + acc[nt][1] * anb.y
                 + acc[nt][2] * anb.z + acc[nt][3] * anb.w;
            psf += acc[nt][0] * asf.x + acc[nt][1] * asf.y
                 + acc[nt][2] * asf.z + acc[nt][3] * asf.w;
            if (avalid) {
                uint2 pk;
                pk.x = (unsigned)f2bf(acc[nt][0]) | ((unsigned)f2bf(acc[nt][1]) << 16);
                pk.y = (unsigned)f2bf(acc[nt][2]) | ((unsigned)f2bf(acc[nt][3]) << 16);
                *(uint2*)(Whb2 + ((size_t)st * N_NODES + arow) * SLICE_COLS + nt * 16 + lk * 4) = pk;
            }
        }
        if ((st & 3) == 3) {
            pnb += __shfl_xor(pnb, 16); pnb += __shfl_xor(pnb, 32);
            psf += __shfl_xor(psf, 16); psf += __shfl_xor(psf, 32);
            if (avalid && lane < 16) {
                e_nb[(size_t)k * N_NODES + arow] = pnb;     // [k][N] layout
                e_self[(size_t)k * N_NODES + arow] = psf;
            }
            pnb = 0.f; psf = 0.f;
        }
        __syncthreads();
    }
}

// ---------------- Kernel 2: XCC-verified sliced gather with wave work-stealing ----------------
// Block reads its REAL XCD id via s_getreg(HW_REG_XCC_ID) [HW-verified, learn_hip m09].
// Waves on XCD x steal 16-node chunks of slice x (first 3125 chunks) then slice x+8.
// Per-XCD cached set: slice 3.2 MB + e_nb[k] 0.2 MB + e_self[k] 0.2 MB = 3.6 MB < 4 MB L2.
// nidx / e_self loads and out stores are non-temporal.
__global__ __launch_bounds__(256) void attn_kernel(
    const int* __restrict__ nidx, const unsigned short* __restrict__ Whb2,
    const float* __restrict__ e_nb, const float* __restrict__ e_self,
    float* __restrict__ out, int* __restrict__ ctr)
{
    unsigned xcc;
    asm volatile("s_getreg_b32 %0, hwreg(HW_REG_XCC_ID)" : "=s"(xcc));
    xcc &= 7;

    const int lane = threadIdx.x & 63;
    const int nl = lane >> 4;               // node subgroup (0..3)
    const int d = lane & 15;                // neighbor slot / col-pair
    const int nchunk = N_NODES / CH;        // 3125

    while (true) {
        int c;
        if (lane == 0) c = atomicAdd(&ctr[xcc], 1);
        c = __shfl(c, 0);
        if (c >= 2 * nchunk) break;
        const int s = (int)xcc + (c >= nchunk ? 8 : 0);
        const int k = s >> 2;               // head
        const int cb = s & 3;               // col-block
        const int base = (c >= nchunk ? c - nchunk : c) * CH;
        const unsigned short* S = Whb2 + (size_t)s * N_NODES * SLICE_COLS;
        const float* enbk = e_nb + (size_t)k * N_NODES;
        const float* esfk = e_self + (size_t)k * N_NODES;

        #pragma unroll
        for (int j = 0; j < CH / 4; ++j) {
            const int n = base + j * 4 + nl;

            const int nbr = __builtin_nontemporal_load(nidx + (size_t)n * D_NB + d);
            const float es = __builtin_nontemporal_load(esfk + n);
            const float x = enbk[nbr] + es;
            const float v = x > 0.f ? x : SLOPE * x;
            float m = v;
            #pragma unroll
            for (int sh = 8; sh >= 1; sh >>= 1) m = fmaxf(m, __shfl_xor(m, sh, 16));
            const float pz = __expf(v - m);
            float sum = pz;
            #pragma unroll
            for (int sh = 8; sh >= 1; sh >>= 1) sum += __shfl_xor(sum, sh, 16);
            const float alpha = pz / sum;

            float a0 = 0.f, a1 = 0.f;
            #pragma unroll
            for (int dd = 0; dd < D_NB; ++dd) {
                const int src = (lane & 48) | dd;
                const float ad = __shfl(alpha, src);
                const int nd = __shfl(nbr, src);
                const unsigned u = *(const unsigned*)(S + (size_t)nd * SLICE_COLS + d * 2);
                a0 += ad * bf2f((unsigned short)(u & 0xffffu));
                a1 += ad * bf2f((unsigned short)(u >> 16));
            }
            f32x2* op = (f32x2*)(out + (size_t)n * (K_HEADS * OUT_DIM) + k * OUT_DIM
                                 + cb * SLICE_COLS + d * 2);
            __builtin_nontemporal_store(f32x2{a0, a1}, op);
        }
    }
}

// ---------------- launch ----------------
extern "C" void kernel_launch(void* const* d_in, const int* in_sizes, int n_in,
                              void* d_out, int out_size, void* d_ws, size_t ws_size,
                              hipStream_t stream) {
    const float* X = (const float*)d_in[0];
    const float* W = (const float*)d_in[1];
    const float* a = (const float*)d_in[2];
    const int* nidx = (const int*)d_in[3];
    float* out = (float*)d_out;

    char* p = (char*)d_ws;
    unsigned short* Wb = (unsigned short*)p;      p += (size_t)K_HEADS * OUT_DIM * IN_DIM * 2;
    unsigned short* Whb2 = (unsigned short*)p;    p += (size_t)NSLICE * N_NODES * SLICE_COLS * 2;
    float* enb = (float*)p;                       p += (size_t)N_NODES * K_HEADS * 4;
    float* eself = (float*)p;                     p += (size_t)N_NODES * K_HEADS * 4;
    int* ctr = (int*)p;

    hipLaunchKernelGGL(wb_kernel,
        dim3((K_HEADS * OUT_DIM * IN_DIM + 255) / 256), dim3(256), 0, stream, W, Wb);

    hipLaunchKernelGGL(gemm_kernel,
        dim3((N_NODES + 63) / 64), dim3(256), 0, stream, X, Wb, a, Whb2, enb, eself);

    hipMemsetAsync(ctr, 0, 8 * sizeof(int), stream);

    hipLaunchKernelGGL(attn_kernel,
        dim3(1024), dim3(256), 0, stream, nidx, Whb2, enb, eself, out, ctr);
}

// Round 12
// 218.788 us; speedup vs baseline: 3.1115x; 3.1115x over previous
//
#include <hip/hip_runtime.h>

#define N_NODES 50000
#define D_NB 16
#define IN_DIM 256
#define OUT_DIM 128
#define K_HEADS 4
#define SLOPE 0.01f
#define NSLICE 16       // slice s = k*4 + cb; 32 cols each
#define SLICE_COLS 32
#define CHUNK 256       // nodes per block-level steal
#define NCHUNKS ((N_NODES + CHUNK - 1) / CHUNK)   // 196

typedef __attribute__((ext_vector_type(8))) short short8;
typedef __attribute__((ext_vector_type(4))) float f32x4;
typedef __attribute__((ext_vector_type(2))) float f32x2;

static __device__ __forceinline__ unsigned short f2bf(float f) {
    unsigned u = __float_as_uint(f);
    unsigned r = u + 0x7fffu + ((u >> 16) & 1u);   // RNE
    return (unsigned short)(r >> 16);
}
static __device__ __forceinline__ float bf2f(unsigned short b) {
    return __uint_as_float(((unsigned)b) << 16);
}

// ---------------- Kernel 0: W (f32) -> Wb (bf16), same [K][OUT][IN] layout ----------------
__global__ void wb_kernel(const float* __restrict__ W, unsigned short* __restrict__ Wb) {
    int id = blockIdx.x * blockDim.x + threadIdx.x;
    if (id < K_HEADS * OUT_DIM * IN_DIM) Wb[id] = f2bf(W[id]);
}

// ---------------- Kernel 1: MFMA GEMM, 64 rows/block, 16 x 16KB double-buffered stages ----------
// e output layout [k][N] (per-head contiguous) for slice-local attn gathers.
__global__ __launch_bounds__(256) void gemm_kernel(
    const float* __restrict__ X, const unsigned short* __restrict__ Wb,
    const float* __restrict__ a,
    unsigned short* __restrict__ Whb2, float* __restrict__ e_nb, float* __restrict__ e_self)
{
    __shared__ unsigned short Wlds[2][SLICE_COLS * IN_DIM];   // 2 x 16 KB

    const int t = threadIdx.x;
    const int lane = t & 63;
    const int w = t >> 6;
    const int lrow = lane & 15;
    const int lk = lane >> 4;
    const int m0 = blockIdx.x * 64 + w * 16;

    const int arow = m0 + lrow;
    const bool avalid = arow < N_NODES;

    const float* Xr = X + (size_t)arow * IN_DIM + lk * 8;
    short8 af[8];
    #pragma unroll
    for (int kk = 0; kk < 8; ++kk) {
        short8 s;
        if (avalid) {
            float4 x0 = *(const float4*)(Xr + kk * 32);
            float4 x1 = *(const float4*)(Xr + kk * 32 + 4);
            s[0] = (short)f2bf(x0.x); s[1] = (short)f2bf(x0.y);
            s[2] = (short)f2bf(x0.z); s[3] = (short)f2bf(x0.w);
            s[4] = (short)f2bf(x1.x); s[5] = (short)f2bf(x1.y);
            s[6] = (short)f2bf(x1.z); s[7] = (short)f2bf(x1.w);
        } else {
            s = short8{0, 0, 0, 0, 0, 0, 0, 0};
        }
        af[kk] = s;
    }

    auto STAGE = [&](int st, int buf) {
        const unsigned short* WbS = Wb + (size_t)st * SLICE_COLS * IN_DIM;
        #pragma unroll
        for (int i = 0; i < 4; ++i) {
            const int c = i * 256 + t;
            const int r = c >> 5;
            const int p = c & 31;
            const int cu = p ^ (r & 7);
            const unsigned short* gsrc = WbS + r * IN_DIM + cu * 8;
            unsigned short* ldst = &Wlds[buf][c * 8];
            __builtin_amdgcn_global_load_lds(
                (const __attribute__((address_space(1))) void*)gsrc,
                (__attribute__((address_space(3))) void*)ldst, 16, 0, 0);
        }
    };

    float pnb = 0.f, psf = 0.f;
    STAGE(0, 0);
    __syncthreads();

    for (int st = 0; st < NSLICE; ++st) {
        const int buf = st & 1;
        if (st + 1 < NSLICE) STAGE(st + 1, buf ^ 1);

        f32x4 acc[2] = {};
        #pragma unroll
        for (int kk = 0; kk < 8; ++kk) {
            #pragma unroll
            for (int nt = 0; nt < 2; ++nt) {
                const int row = nt * 16 + lrow;
                const int pos = (kk * 4 + lk) ^ (row & 7);
                const short8 bf = *(const short8*)(&Wlds[buf][row * IN_DIM + pos * 8]);
                acc[nt] = __builtin_amdgcn_mfma_f32_16x16x32_bf16(bf, af[kk], acc[nt], 0, 0, 0);
            }
        }

        const int k = st >> 2, cb = st & 3;
        #pragma unroll
        for (int nt = 0; nt < 2; ++nt) {
            const float4 anb = *(const float4*)(a + k * 2 * OUT_DIM + cb * 32 + nt * 16 + lk * 4);
            const float4 asf = *(const float4*)(a + k * 2 * OUT_DIM + OUT_DIM + cb * 32 + nt * 16 + lk * 4);
            pnb += acc[nt][0] * anb.x + acc[nt][1] * anb.y
                 + acc[nt][2] * anb.z + acc[nt][3] * anb.w;
            psf += acc[nt][0] * asf.x + acc[nt][1] * asf.y
                 + acc[nt][2] * asf.z + acc[nt][3] * asf.w;
            if (avalid) {
                uint2 pk;
                pk.x = (unsigned)f2bf(acc[nt][0]) | ((unsigned)f2bf(acc[nt][1]) << 16);
                pk.y = (unsigned)f2bf(acc[nt][2]) | ((unsigned)f2bf(acc[nt][3]) << 16);
                *(uint2*)(Whb2 + ((size_t)st * N_NODES + arow) * SLICE_COLS + nt * 16 + lk * 4) = pk;
            }
        }
        if ((st & 3) == 3) {
            pnb += __shfl_xor(pnb, 16); pnb += __shfl_xor(pnb, 32);
            psf += __shfl_xor(psf, 16); psf += __shfl_xor(psf, 32);
            if (avalid && lane < 16) {
                e_nb[(size_t)k * N_NODES + arow] = pnb;     // [k][N] layout
                e_self[(size_t)k * N_NODES + arow] = psf;
            }
            pnb = 0.f; psf = 0.f;
        }
        __syncthreads();
    }
}

// ---------------- Kernel 2: XCC-verified sliced gather, block-level work stealing ----------------
// Block reads its REAL XCD id via s_getreg(HW_REG_XCC_ID) [HW-verified, learn_hip m09].
// Blocks on XCD x steal 256-node chunks of slice x (chunks 0..195) then slice x+8 (196..391).
// Counters padded 128B apart -> each counter is XCD-private (no cross-XCD line migration).
// Per-XCD cached set: slice 3.2 MB + e_nb[k] 0.2 MB = 3.4 MB < 4 MB L2.
__global__ __launch_bounds__(256) void attn_kernel(
    const int* __restrict__ nidx, const unsigned short* __restrict__ Whb2,
    const float* __restrict__ e_nb, const float* __restrict__ e_self,
    float* __restrict__ out, int* __restrict__ ctr)
{
    unsigned xcc;
    asm volatile("s_getreg_b32 %0, hwreg(HW_REG_XCC_ID)" : "=s"(xcc));
    xcc &= 7;

    __shared__ int c_sh;
    const int t = threadIdx.x;
    const int w = t >> 6;
    const int lane = t & 63;
    const int nl = lane >> 4;               // node subgroup (0..3)
    const int d = lane & 15;                // neighbor slot / col-pair

    while (true) {
        __syncthreads();                    // previous iteration's c_sh reads done
        if (t == 0) c_sh = atomicAdd(&ctr[xcc * 32], 1);
        __syncthreads();
        const int c = c_sh;
        if (c >= 2 * NCHUNKS) break;

        const int s = (int)xcc + (c >= NCHUNKS ? 8 : 0);
        const int k = s >> 2;               // head
        const int cb = s & 3;               // col-block
        const int base = (c >= NCHUNKS ? c - NCHUNKS : c) * CHUNK + w * (CHUNK / 4);
        const unsigned short* S = Whb2 + (size_t)s * N_NODES * SLICE_COLS;
        const float* enbk = e_nb + (size_t)k * N_NODES;
        const float* esfk = e_self + (size_t)k * N_NODES;

        #pragma unroll 4
        for (int j = 0; j < CHUNK / 16; ++j) {     // 16 j-iters x 4 nodes/wave
            const int n = base + j * 4 + nl;
            if (n < N_NODES) {
                const int nbr = __builtin_nontemporal_load(nidx + (size_t)n * D_NB + d);
                const float es = __builtin_nontemporal_load(esfk + n);
                const float x = enbk[nbr] + es;
                const float v = x > 0.f ? x : SLOPE * x;
                float m = v;
                #pragma unroll
                for (int sh = 8; sh >= 1; sh >>= 1) m = fmaxf(m, __shfl_xor(m, sh, 16));
                const float pz = __expf(v - m);
                float sum = pz;
                #pragma unroll
                for (int sh = 8; sh >= 1; sh >>= 1) sum += __shfl_xor(sum, sh, 16);
                const float alpha = pz / sum;

                float a0 = 0.f, a1 = 0.f;
                #pragma unroll
                for (int dd = 0; dd < D_NB; ++dd) {
                    const int src = (lane & 48) | dd;
                    const float ad = __shfl(alpha, src);
                    const int nd = __shfl(nbr, src);
                    const unsigned u = *(const unsigned*)(S + (size_t)nd * SLICE_COLS + d * 2);
                    a0 += ad * bf2f((unsigned short)(u & 0xffffu));
                    a1 += ad * bf2f((unsigned short)(u >> 16));
                }
                f32x2* op = (f32x2*)(out + (size_t)n * (K_HEADS * OUT_DIM) + k * OUT_DIM
                                     + cb * SLICE_COLS + d * 2);
                __builtin_nontemporal_store(f32x2{a0, a1}, op);
            }
        }
    }
}

// ---------------- launch ----------------
extern "C" void kernel_launch(void* const* d_in, const int* in_sizes, int n_in,
                              void* d_out, int out_size, void* d_ws, size_t ws_size,
                              hipStream_t stream) {
    const float* X = (const float*)d_in[0];
    const float* W = (const float*)d_in[1];
    const float* a = (const float*)d_in[2];
    const int* nidx = (const int*)d_in[3];
    float* out = (float*)d_out;

    char* p = (char*)d_ws;
    unsigned short* Wb = (unsigned short*)p;      p += (size_t)K_HEADS * OUT_DIM * IN_DIM * 2;
    unsigned short* Whb2 = (unsigned short*)p;    p += (size_t)NSLICE * N_NODES * SLICE_COLS * 2;
    float* enb = (float*)p;                       p += (size_t)N_NODES * K_HEADS * 4;
    float* eself = (float*)p;                     p += (size_t)N_NODES * K_HEADS * 4;
    int* ctr = (int*)p;                           // 8 counters, 128B apart

    hipLaunchKernelGGL(wb_kernel,
        dim3((K_HEADS * OUT_DIM * IN_DIM + 255) / 256), dim3(256), 0, stream, W, Wb);

    hipLaunchKernelGGL(gemm_kernel,
        dim3((N_NODES + 63) / 64), dim3(256), 0, stream, X, Wb, a, Whb2, enb, eself);

    hipMemsetAsync(ctr, 0, 8 * 32 * sizeof(int), stream);

    hipLaunchKernelGGL(attn_kernel,
        dim3(1024), dim3(256), 0, stream, nidx, Whb2, enb, eself, out, ctr);
}

// Round 13
// 193.960 us; speedup vs baseline: 3.5098x; 1.1280x over previous
//
#include <hip/hip_runtime.h>

#define N_NODES 50000
#define D_NB 16
#define IN_DIM 256
#define OUT_DIM 128
#define K_HEADS 4
#define SLOPE 0.01f
#define NSLICE 16       // slice s = k*4 + cb; 32 cols each
#define SLICE_COLS 32
#define CHUNK 256       // nodes per block-level steal
#define NCHUNKS ((N_NODES + CHUNK - 1) / CHUNK)   // 196

typedef __attribute__((ext_vector_type(8))) short short8;
typedef __attribute__((ext_vector_type(4))) float f32x4;
typedef __attribute__((ext_vector_type(2))) float f32x2;

static __device__ __forceinline__ unsigned short f2bf(float f) {
    unsigned u = __float_as_uint(f);
    unsigned r = u + 0x7fffu + ((u >> 16) & 1u);   // RNE
    return (unsigned short)(r >> 16);
}
static __device__ __forceinline__ float bf2f(unsigned short b) {
    return __uint_as_float(((unsigned)b) << 16);
}

// ---------------- Kernel 0: W (f32) -> Wb (bf16), same [K][OUT][IN] layout ----------------
__global__ void wb_kernel(const float* __restrict__ W, unsigned short* __restrict__ Wb) {
    int id = blockIdx.x * blockDim.x + threadIdx.x;
    if (id < K_HEADS * OUT_DIM * IN_DIM) Wb[id] = f2bf(W[id]);
}

// ---------------- Kernel 1: MFMA GEMM (unchanged from round 12; e layout [k][N]) ----------------
__global__ __launch_bounds__(256) void gemm_kernel(
    const float* __restrict__ X, const unsigned short* __restrict__ Wb,
    const float* __restrict__ a,
    unsigned short* __restrict__ Whb2, float* __restrict__ e_nb, float* __restrict__ e_self)
{
    __shared__ unsigned short Wlds[2][SLICE_COLS * IN_DIM];   // 2 x 16 KB

    const int t = threadIdx.x;
    const int lane = t & 63;
    const int w = t >> 6;
    const int lrow = lane & 15;
    const int lk = lane >> 4;
    const int m0 = blockIdx.x * 64 + w * 16;

    const int arow = m0 + lrow;
    const bool avalid = arow < N_NODES;

    const float* Xr = X + (size_t)arow * IN_DIM + lk * 8;
    short8 af[8];
    #pragma unroll
    for (int kk = 0; kk < 8; ++kk) {
        short8 s;
        if (avalid) {
            float4 x0 = *(const float4*)(Xr + kk * 32);
            float4 x1 = *(const float4*)(Xr + kk * 32 + 4);
            s[0] = (short)f2bf(x0.x); s[1] = (short)f2bf(x0.y);
            s[2] = (short)f2bf(x0.z); s[3] = (short)f2bf(x0.w);
            s[4] = (short)f2bf(x1.x); s[5] = (short)f2bf(x1.y);
            s[6] = (short)f2bf(x1.z); s[7] = (short)f2bf(x1.w);
        } else {
            s = short8{0, 0, 0, 0, 0, 0, 0, 0};
        }
        af[kk] = s;
    }

    auto STAGE = [&](int st, int buf) {
        const unsigned short* WbS = Wb + (size_t)st * SLICE_COLS * IN_DIM;
        #pragma unroll
        for (int i = 0; i < 4; ++i) {
            const int c = i * 256 + t;
            const int r = c >> 5;
            const int p = c & 31;
            const int cu = p ^ (r & 7);
            const unsigned short* gsrc = WbS + r * IN_DIM + cu * 8;
            unsigned short* ldst = &Wlds[buf][c * 8];
            __builtin_amdgcn_global_load_lds(
                (const __attribute__((address_space(1))) void*)gsrc,
                (__attribute__((address_space(3))) void*)ldst, 16, 0, 0);
        }
    };

    float pnb = 0.f, psf = 0.f;
    STAGE(0, 0);
    __syncthreads();

    for (int st = 0; st < NSLICE; ++st) {
        const int buf = st & 1;
        if (st + 1 < NSLICE) STAGE(st + 1, buf ^ 1);

        f32x4 acc[2] = {};
        #pragma unroll
        for (int kk = 0; kk < 8; ++kk) {
            #pragma unroll
            for (int nt = 0; nt < 2; ++nt) {
                const int row = nt * 16 + lrow;
                const int pos = (kk * 4 + lk) ^ (row & 7);
                const short8 bf = *(const short8*)(&Wlds[buf][row * IN_DIM + pos * 8]);
                acc[nt] = __builtin_amdgcn_mfma_f32_16x16x32_bf16(bf, af[kk], acc[nt], 0, 0, 0);
            }
        }

        const int k = st >> 2, cb = st & 3;
        #pragma unroll
        for (int nt = 0; nt < 2; ++nt) {
            const float4 anb = *(const float4*)(a + k * 2 * OUT_DIM + cb * 32 + nt * 16 + lk * 4);
            const float4 asf = *(const float4*)(a + k * 2 * OUT_DIM + OUT_DIM + cb * 32 + nt * 16 + lk * 4);
            pnb += acc[nt][0] * anb.x + acc[nt][1] * anb.y
                 + acc[nt][2] * anb.z + acc[nt][3] * anb.w;
            psf += acc[nt][0] * asf.x + acc[nt][1] * asf.y
                 + acc[nt][2] * asf.z + acc[nt][3] * asf.w;
            if (avalid) {
                uint2 pk;
                pk.x = (unsigned)f2bf(acc[nt][0]) | ((unsigned)f2bf(acc[nt][1]) << 16);
                pk.y = (unsigned)f2bf(acc[nt][2]) | ((unsigned)f2bf(acc[nt][3]) << 16);
                *(uint2*)(Whb2 + ((size_t)st * N_NODES + arow) * SLICE_COLS + nt * 16 + lk * 4) = pk;
            }
        }
        if ((st & 3) == 3) {
            pnb += __shfl_xor(pnb, 16); pnb += __shfl_xor(pnb, 32);
            psf += __shfl_xor(psf, 16); psf += __shfl_xor(psf, 32);
            if (avalid && lane < 16) {
                e_nb[(size_t)k * N_NODES + arow] = pnb;     // [k][N] layout
                e_self[(size_t)k * N_NODES + arow] = psf;
            }
            pnb = 0.f; psf = 0.f;
        }
        __syncthreads();
    }
}

// ---------------- Kernel 2a: softmax -> alpha[k][n][16] f32 (once per node,head) ----------------
// Wave = 4 nodes x 16 nbr-lanes. The random e_nb[nbr] gather happens exactly once per (n,k).
__global__ __launch_bounds__(256) void alpha_kernel(
    const int* __restrict__ nidx, const float* __restrict__ e_nb,
    const float* __restrict__ e_self, float* __restrict__ alpha)
{
    const int t = threadIdx.x;
    const int w = t >> 6;
    const int lane = t & 63;
    const int nl = lane >> 4;
    const int d = lane & 15;
    const int n = (blockIdx.x * 4 + w) * 4 + nl;

    const int nbr = __builtin_nontemporal_load(nidx + (size_t)n * D_NB + d);
    #pragma unroll
    for (int k = 0; k < K_HEADS; ++k) {
        const float es = e_self[(size_t)k * N_NODES + n];
        const float x = e_nb[(size_t)k * N_NODES + nbr] + es;
        const float v = x > 0.f ? x : SLOPE * x;
        float m = v;
        #pragma unroll
        for (int sh = 8; sh >= 1; sh >>= 1) m = fmaxf(m, __shfl_xor(m, sh, 16));
        const float pz = __expf(v - m);
        float sum = pz;
        #pragma unroll
        for (int sh = 8; sh >= 1; sh >>= 1) sum += __shfl_xor(sum, sh, 16);
        __builtin_nontemporal_store(pz / sum,
            alpha + ((size_t)k * N_NODES + n) * D_NB + d);
    }
}

// ---------------- Kernel 2b: XCC-sliced gather, pure weighted sum ----------------
// Block reads its REAL XCD id via s_getreg(HW_REG_XCC_ID); blocks on XCD x steal 256-node
// chunks of slice x then slice x+8 (counters 128B apart). Per-XCD cached set: slice 3.2 MB.
// 8 lanes per node, 8 B/lane gathers; nidx/alpha streamed nontemporal; out nontemporal.
__global__ __launch_bounds__(256) void gather_kernel(
    const int* __restrict__ nidx, const unsigned short* __restrict__ Whb2,
    const float* __restrict__ alpha, float* __restrict__ out, int* __restrict__ ctr)
{
    unsigned xcc;
    asm volatile("s_getreg_b32 %0, hwreg(HW_REG_XCC_ID)" : "=s"(xcc));
    xcc &= 7;

    __shared__ int c_sh;
    const int t = threadIdx.x;
    const int w = t >> 6;
    const int lane = t & 63;
    const int g = lane >> 3;                // node subgroup (0..7)
    const int c = lane & 7;                 // col-quad (4 cols = 8 B)

    while (true) {
        __syncthreads();
        if (t == 0) c_sh = atomicAdd(&ctr[xcc * 32], 1);
        __syncthreads();
        const int ch = c_sh;
        if (ch >= 2 * NCHUNKS) break;

        const int s = (int)xcc + (ch >= NCHUNKS ? 8 : 0);
        const int k = s >> 2;               // head
        const int cb = s & 3;               // col-block
        const int base = (ch >= NCHUNKS ? ch - NCHUNKS : ch) * CHUNK + w * (CHUNK / 4);
        const unsigned short* S = Whb2 + (size_t)s * N_NODES * SLICE_COLS;
        const float* A = alpha + (size_t)k * N_NODES * D_NB;

        #pragma unroll
        for (int j = 0; j < CHUNK / 32; ++j) {     // 8 j-iters x 8 nodes/wave
            const int n = base + j * 8 + g;
            if (n < N_NODES) {
                const int   nb_lo = __builtin_nontemporal_load(nidx + (size_t)n * D_NB + c);
                const int   nb_hi = __builtin_nontemporal_load(nidx + (size_t)n * D_NB + c + 8);
                const float a_lo  = __builtin_nontemporal_load(A + (size_t)n * D_NB + c);
                const float a_hi  = __builtin_nontemporal_load(A + (size_t)n * D_NB + c + 8);

                float acc0 = 0.f, acc1 = 0.f, acc2 = 0.f, acc3 = 0.f;
                #pragma unroll
                for (int dd = 0; dd < D_NB; ++dd) {
                    const int src = (lane & 56) | (dd & 7);
                    const float ad = __shfl(dd < 8 ? a_lo : a_hi, src);
                    const int   nd = __shfl(dd < 8 ? nb_lo : nb_hi, src);
                    const uint2 u = *(const uint2*)(S + (size_t)nd * SLICE_COLS + c * 4);
                    acc0 += ad * bf2f((unsigned short)(u.x & 0xffffu));
                    acc1 += ad * bf2f((unsigned short)(u.x >> 16));
                    acc2 += ad * bf2f((unsigned short)(u.y & 0xffffu));
                    acc3 += ad * bf2f((unsigned short)(u.y >> 16));
                }
                f32x4* op = (f32x4*)(out + (size_t)n * (K_HEADS * OUT_DIM) + k * OUT_DIM
                                     + cb * SLICE_COLS + c * 4);
                __builtin_nontemporal_store(f32x4{acc0, acc1, acc2, acc3}, op);
            }
        }
    }
}

// ---------------- launch ----------------
extern "C" void kernel_launch(void* const* d_in, const int* in_sizes, int n_in,
                              void* d_out, int out_size, void* d_ws, size_t ws_size,
                              hipStream_t stream) {
    const float* X = (const float*)d_in[0];
    const float* W = (const float*)d_in[1];
    const float* a = (const float*)d_in[2];
    const int* nidx = (const int*)d_in[3];
    float* out = (float*)d_out;

    char* p = (char*)d_ws;
    unsigned short* Wb = (unsigned short*)p;      p += (size_t)K_HEADS * OUT_DIM * IN_DIM * 2;
    unsigned short* Whb2 = (unsigned short*)p;    p += (size_t)NSLICE * N_NODES * SLICE_COLS * 2;
    float* enb = (float*)p;                       p += (size_t)N_NODES * K_HEADS * 4;
    float* eself = (float*)p;                     p += (size_t)N_NODES * K_HEADS * 4;
    float* alpha = (float*)p;                     p += (size_t)K_HEADS * N_NODES * D_NB * 4;
    int* ctr = (int*)p;                           // 8 counters, 128B apart

    hipLaunchKernelGGL(wb_kernel,
        dim3((K_HEADS * OUT_DIM * IN_DIM + 255) / 256), dim3(256), 0, stream, W, Wb);

    hipLaunchKernelGGL(gemm_kernel,
        dim3((N_NODES + 63) / 64), dim3(256), 0, stream, X, Wb, a, Whb2, enb, eself);

    hipMemsetAsync(ctr, 0, 8 * 32 * sizeof(int), stream);

    hipLaunchKernelGGL(alpha_kernel,
        dim3(N_NODES / 16), dim3(256), 0, stream, nidx, enb, eself, alpha);

    hipLaunchKernelGGL(gather_kernel,
        dim3(1024), dim3(256), 0, stream, nidx, Whb2, alpha, out, ctr);
}